// Round 3
// baseline (191.265 us; speedup 1.0000x reference)
//
#include <hip/hip_runtime.h>
#include <math.h>

#define NB 16
#define DIN 512
#define TT 4096
#define DCB 8
#define KC 1024
#define NW 8            // waves per block

// ws layout (floats):
// [0,4096)      w_inT[d][c]   (transposed)
// [4096,8192)   w_out[o][c]
// [8192,9216)   cb2[k]
// [9216,10240)  per-block commit partials (1024)

__global__ __launch_bounds__(512) void vq_setup(
    const float* __restrict__ in_v, const float* __restrict__ in_g,
    const float* __restrict__ out_v, const float* __restrict__ out_g,
    const float* __restrict__ cb, float* __restrict__ ws)
{
    int tid = threadIdx.x;
    float* w_inT = ws;
    float* w_out = ws + 4096;
    float* cb2   = ws + 8192;

    // --- w_in: 8 rows of 512; one wave per row ---
    {
        int c    = tid >> 6;
        int lane = tid & 63;
        const float* v = in_v + c * DIN;
        float s = 0.f;
        #pragma unroll
        for (int i = 0; i < DIN; i += 64) {
            float x = v[i + lane];
            s += x * x;
        }
        #pragma unroll
        for (int off = 32; off > 0; off >>= 1) s += __shfl_xor(s, off, 64);
        float sq = sqrtf(s);
        float g  = in_g[c];
        #pragma unroll
        for (int i = 0; i < DIN; i += 64) {
            int d = i + lane;
            w_inT[d * DCB + c] = (g * v[d]) / sq;
        }
    }
    // --- w_out: 512 rows of 8 ---
    {
        int o = tid;
        const float* v = out_v + o * DCB;
        float s = 0.f;
        #pragma unroll
        for (int c = 0; c < DCB; ++c) s += v[c] * v[c];
        float sq = sqrtf(s);
        float g  = out_g[o];
        #pragma unroll
        for (int c = 0; c < DCB; ++c) w_out[o * DCB + c] = (g * v[c]) / sq;
    }
    // --- cb2 ---
    for (int k = tid; k < KC; k += 512) {
        const float* r = cb + k * DCB;
        float s = 0.f;
        #pragma unroll
        for (int c = 0; c < DCB; ++c) s += r[c] * r[c];
        cb2[k] = s;
    }
}

__global__ __launch_bounds__(512, 8) void vq_main(
    const float* __restrict__ z, const float* __restrict__ in_b,
    const float* __restrict__ out_b, const float* __restrict__ cb,
    const float* __restrict__ ws, float* __restrict__ ws_commit,
    float* __restrict__ out)
{
    const float* w_inT = ws;
    const float* w_out = ws + 4096;
    const float* cb2   = ws + 8192;

    __shared__ float red[DCB][NW][64];   // 16 KB
    __shared__ float sd[NW][64];         // 2 KB
    __shared__ int   si[NW][64];         // 2 KB

    int w    = threadIdx.x >> 6;         // 0..7
    int lane = threadIdx.x & 63;
    int blk  = blockIdx.x;               // 0..1023
    int b    = blk >> 6;
    int t    = (blk & 63) * 64 + lane;

    const float* zp = z + (size_t)b * DIN * TT + t;

    // ---- partial in-projection over d in [w*64, w*64+64) ----
    float ze[DCB];
    #pragma unroll
    for (int c = 0; c < DCB; ++c) ze[c] = 0.f;

    int d0 = w * 64;
    #pragma unroll 8
    for (int dd = 0; dd < 64; ++dd) {
        int d = d0 + dd;
        float zv = zp[(size_t)d * TT];       // coalesced across lanes
        const float* wi = w_inT + d * DCB;   // wave-uniform -> s_load
        #pragma unroll
        for (int c = 0; c < DCB; ++c) ze[c] = fmaf(wi[c], zv, ze[c]);
    }

    // ---- cross-wave reduce of ze ----
    #pragma unroll
    for (int c = 0; c < DCB; ++c) red[c][w][lane] = ze[c];
    __syncthreads();
    #pragma unroll
    for (int c = 0; c < DCB; ++c) {
        float s = (((red[c][0][lane] + red[c][1][lane]) +
                    (red[c][2][lane] + red[c][3][lane])) +
                   ((red[c][4][lane] + red[c][5][lane]) +
                    (red[c][6][lane] + red[c][7][lane])));
        ze[c] = s + in_b[c];
    }

    // ---- codebook partial argmin over k in [w*128, w*128+128) ----
    float enc2 = 0.f;
    #pragma unroll
    for (int c = 0; c < DCB; ++c) enc2 += ze[c] * ze[c];

    float best = 3.4e38f;
    int   bi   = 0;
    int   k0   = w * 128;
    #pragma unroll 8
    for (int kk = 0; kk < 128; ++kk) {
        int k = k0 + kk;
        const float* r = cb + k * DCB;       // wave-uniform -> s_load_dwordx8
        float dot = 0.f;
        #pragma unroll
        for (int c = 0; c < DCB; ++c) dot = fmaf(ze[c], r[c], dot);
        float dk = (enc2 - 2.0f * dot) + cb2[k];
        if (dk < best) { best = dk; bi = k; }
    }
    sd[w][lane] = best;
    si[w][lane] = bi;
    __syncthreads();

    // ordered combine (w'=0..7, strict < keeps first min over k)
    float gbest = sd[0][lane];
    int   gbi   = si[0][lane];
    #pragma unroll
    for (int w2 = 1; w2 < NW; ++w2) {
        float d2 = sd[w2][lane];
        int   i2 = si[w2][lane];
        if (d2 < gbest) { gbest = d2; gbi = i2; }
    }

    // ---- z_q gather, straight-through value, commit loss ----
    const float* cq = cb + (size_t)gbi * DCB;
    float zst[DCB];
    float cl = 0.f;
    #pragma unroll
    for (int c = 0; c < DCB; ++c) {
        float q    = cq[c];
        float diff = ze[c] - q;
        cl = fmaf(diff, diff, cl);
        zst[c] = ze[c] + (q - ze[c]);        // match z_e + stopgrad(z_q - z_e)
    }
    if (w == 0) {
        #pragma unroll
        for (int off = 32; off > 0; off >>= 1) cl += __shfl_xor(cl, off, 64);
        if (lane == 0) ws_commit[blk] = cl;
        // indices (as float; whole out buffer is read as fp32)
        out[(size_t)NB * DIN * TT + NB + (size_t)b * TT + t] = (float)gbi;
    }

    // ---- out-projection over o in [w*64, w*64+64) ----
    float* outp = out + (size_t)b * DIN * TT + t;
    int o0 = w * 64;
    #pragma unroll 4
    for (int oo = 0; oo < 64; ++oo) {
        int o = o0 + oo;
        const float* wo = w_out + o * DCB;   // wave-uniform -> s_load
        float acc = 0.f;
        #pragma unroll
        for (int c = 0; c < DCB; ++c) acc = fmaf(wo[c], zst[c], acc);
        outp[(size_t)o * TT] = acc + out_b[o];
    }
}

__global__ __launch_bounds__(64) void vq_commit(
    const float* __restrict__ ws_commit, float* __restrict__ out)
{
    int b    = blockIdx.x;
    int lane = threadIdx.x;
    float s = ws_commit[b * 64 + lane];
    #pragma unroll
    for (int off = 32; off > 0; off >>= 1) s += __shfl_xor(s, off, 64);
    if (lane == 0)
        out[(size_t)NB * DIN * TT + b] = s * (1.0f / (DCB * TT));
}

extern "C" void kernel_launch(void* const* d_in, const int* in_sizes, int n_in,
                              void* d_out, int out_size, void* d_ws, size_t ws_size,
                              hipStream_t stream) {
    const float* z     = (const float*)d_in[0];
    const float* in_v  = (const float*)d_in[1];
    const float* in_g  = (const float*)d_in[2];
    const float* in_b  = (const float*)d_in[3];
    const float* out_v = (const float*)d_in[4];
    const float* out_g = (const float*)d_in[5];
    const float* out_b = (const float*)d_in[6];
    const float* cb    = (const float*)d_in[7];

    float* ws  = (float*)d_ws;
    float* out = (float*)d_out;

    vq_setup<<<1, 512, 0, stream>>>(in_v, in_g, out_v, out_g, cb, ws);
    vq_main<<<1024, 512, 0, stream>>>(z, in_b, out_b, cb, ws, ws + 9216, out);
    vq_commit<<<NB, 64, 0, stream>>>(ws + 9216, out);
}

// Round 4
// 73.129 us; speedup vs baseline: 2.6154x; 2.6154x over previous
//
#include <hip/hip_runtime.h>
#include <math.h>

#define NB 16
#define DIN 512
#define TT 4096
#define DCB 8
#define KC 1024
#define NW 8            // waves per block
#define TC 128          // t-chunk per block (2 per lane, float2)

// ws layout (floats):
// [0,4096)      w_inT[d][c]   (transposed)
// [4096,8192)   w_out[o][c]
// [8192,9216)   cb2[k]
// [9216,9728)   per-block commit partials (512)

__global__ __launch_bounds__(512) void vq_setup(
    const float* __restrict__ in_v, const float* __restrict__ in_g,
    const float* __restrict__ out_v, const float* __restrict__ out_g,
    const float* __restrict__ cb, float* __restrict__ ws)
{
    int tid = threadIdx.x;
    float* w_inT = ws;
    float* w_out = ws + 4096;
    float* cb2   = ws + 8192;

    // --- w_in: 8 rows of 512; one wave per row ---
    {
        int c    = tid >> 6;
        int lane = tid & 63;
        const float* v = in_v + c * DIN;
        float s = 0.f;
        #pragma unroll
        for (int i = 0; i < DIN; i += 64) {
            float x = v[i + lane];
            s += x * x;
        }
        #pragma unroll
        for (int off = 32; off > 0; off >>= 1) s += __shfl_xor(s, off, 64);
        float sq = sqrtf(s);
        float g  = in_g[c];
        #pragma unroll
        for (int i = 0; i < DIN; i += 64) {
            int d = i + lane;
            w_inT[d * DCB + c] = (g * v[d]) / sq;
        }
    }
    // --- w_out: 512 rows of 8 ---
    {
        int o = tid;
        const float* v = out_v + o * DCB;
        float s = 0.f;
        #pragma unroll
        for (int c = 0; c < DCB; ++c) s += v[c] * v[c];
        float sq = sqrtf(s);
        float g  = out_g[o];
        #pragma unroll
        for (int c = 0; c < DCB; ++c) w_out[o * DCB + c] = (g * v[c]) / sq;
    }
    // --- cb2 ---
    for (int k = tid; k < KC; k += 512) {
        const float* r = cb + k * DCB;
        float s = 0.f;
        #pragma unroll
        for (int c = 0; c < DCB; ++c) s += r[c] * r[c];
        cb2[k] = s;
    }
}

__global__ __launch_bounds__(512, 4) void vq_main(
    const float* __restrict__ z, const float* __restrict__ in_b,
    const float* __restrict__ out_b, const float* __restrict__ cb,
    const float* __restrict__ ws, float* __restrict__ ws_commit,
    float* __restrict__ out)
{
    const float* w_inT = ws;
    const float* w_out = ws + 4096;
    const float* cb2   = ws + 8192;

    __shared__ float red[NW][DCB][TC];   // 32 KB
    __shared__ float sd[NW][TC];         // 4 KB
    __shared__ int   si[NW][TC];         // 4 KB
    __shared__ float scl[NW];

    int w    = threadIdx.x >> 6;
    int wu   = __builtin_amdgcn_readfirstlane(w);   // provably wave-uniform
    int lane = threadIdx.x & 63;
    int blk  = blockIdx.x;               // 0..511
    int b    = blk >> 5;
    int t0   = (blk & 31) * TC;
    int tl   = 2 * lane;                 // lane's local t-pair

    const float* zp = z + (size_t)b * DIN * TT + t0 + tl;

    // ---- partial in-projection over d in [wu*64, wu*64+64), float2 over t ----
    float ze0[DCB], ze1[DCB];
    #pragma unroll
    for (int c = 0; c < DCB; ++c) { ze0[c] = 0.f; ze1[c] = 0.f; }

    int d0 = wu * 64;
    #pragma unroll 4
    for (int dd = 0; dd < 64; ++dd) {
        int d = d0 + dd;
        float2 zv = *(const float2*)(zp + (size_t)d * TT);  // 512 B/wave, contiguous
        const float* wi = w_inT + d * DCB;                  // wave-uniform -> s_load
        #pragma unroll
        for (int c = 0; c < DCB; ++c) {
            ze0[c] = fmaf(wi[c], zv.x, ze0[c]);
            ze1[c] = fmaf(wi[c], zv.y, ze1[c]);
        }
    }

    // ---- cross-wave reduce of ze ----
    #pragma unroll
    for (int c = 0; c < DCB; ++c) {
        red[w][c][tl]     = ze0[c];
        red[w][c][tl + 1] = ze1[c];
    }
    __syncthreads();
    #pragma unroll
    for (int c = 0; c < DCB; ++c) {
        float s0 = 0.f, s1 = 0.f;
        #pragma unroll
        for (int w2 = 0; w2 < NW; ++w2) {
            s0 += red[w2][c][tl];
            s1 += red[w2][c][tl + 1];
        }
        ze0[c] = s0 + in_b[c];
        ze1[c] = s1 + in_b[c];
    }

    // ---- codebook partial argmin over k in [wu*128, wu*128+128) ----
    float enc20 = 0.f, enc21 = 0.f;
    #pragma unroll
    for (int c = 0; c < DCB; ++c) {
        enc20 += ze0[c] * ze0[c];
        enc21 += ze1[c] * ze1[c];
    }

    float best0 = 3.4e38f, best1 = 3.4e38f;
    int   bi0   = 0,       bi1   = 0;
    int   k0    = wu * 128;
    #pragma unroll 4
    for (int kk = 0; kk < 128; ++kk) {
        int k = k0 + kk;
        const float* r = cb + k * DCB;       // wave-uniform -> s_load_dwordx8
        float dot0 = 0.f, dot1 = 0.f;
        #pragma unroll
        for (int c = 0; c < DCB; ++c) {
            dot0 = fmaf(ze0[c], r[c], dot0);
            dot1 = fmaf(ze1[c], r[c], dot1);
        }
        float c2 = cb2[k];
        float dk0 = (enc20 - 2.0f * dot0) + c2;
        float dk1 = (enc21 - 2.0f * dot1) + c2;
        if (dk0 < best0) { best0 = dk0; bi0 = k; }
        if (dk1 < best1) { best1 = dk1; bi1 = k; }
    }
    sd[w][tl]     = best0;  si[w][tl]     = bi0;
    sd[w][tl + 1] = best1;  si[w][tl + 1] = bi1;
    __syncthreads();

    // ordered combine (w'=0..7, strict < keeps first min over k)
    float g0 = sd[0][tl], g1 = sd[0][tl + 1];
    int  gi0 = si[0][tl], gi1 = si[0][tl + 1];
    #pragma unroll
    for (int w2 = 1; w2 < NW; ++w2) {
        float d0_ = sd[w2][tl],     d1_ = sd[w2][tl + 1];
        int   i0_ = si[w2][tl],     i1_ = si[w2][tl + 1];
        if (d0_ < g0) { g0 = d0_; gi0 = i0_; }
        if (d1_ < g1) { g1 = d1_; gi1 = i1_; }
    }

    // ---- z_q gather, straight-through value, commit loss ----
    const float* cq0 = cb + (size_t)gi0 * DCB;
    const float* cq1 = cb + (size_t)gi1 * DCB;
    float zst0[DCB], zst1[DCB];
    float cl = 0.f;
    #pragma unroll
    for (int c = 0; c < DCB; ++c) {
        float q0 = cq0[c], q1 = cq1[c];
        float f0 = ze0[c] - q0, f1 = ze1[c] - q1;
        cl = fmaf(f0, f0, cl);
        cl = fmaf(f1, f1, cl);
        zst0[c] = ze0[c] + (q0 - ze0[c]);    // match z_e + stopgrad(z_q - z_e)
        zst1[c] = ze1[c] + (q1 - ze1[c]);
    }
    #pragma unroll
    for (int off = 32; off > 0; off >>= 1) cl += __shfl_xor(cl, off, 64);
    if (lane == 0) scl[w] = cl;

    if (wu == 0) {
        // indices (as float; whole out buffer is read as fp32)
        float2 iv = make_float2((float)gi0, (float)gi1);
        *(float2*)(out + (size_t)NB * DIN * TT + NB + (size_t)b * TT + t0 + tl) = iv;
    }

    // ---- out-projection over o in [wu*64, wu*64+64), float2 stores ----
    float* outp = out + (size_t)b * DIN * TT + t0 + tl;
    int o0 = wu * 64;
    #pragma unroll 4
    for (int oo = 0; oo < 64; ++oo) {
        int o = o0 + oo;
        const float* wo = w_out + o * DCB;   // wave-uniform -> s_load
        float a0 = 0.f, a1 = 0.f;
        #pragma unroll
        for (int c = 0; c < DCB; ++c) {
            a0 = fmaf(wo[c], zst0[c], a0);
            a1 = fmaf(wo[c], zst1[c], a1);
        }
        float ob = out_b[o];
        *(float2*)(outp + (size_t)o * TT) = make_float2(a0 + ob, a1 + ob);  // 512 B/wave
    }

    __syncthreads();
    if (threadIdx.x == 0) {
        float s = 0.f;
        #pragma unroll
        for (int w2 = 0; w2 < NW; ++w2) s += scl[w2];
        ws_commit[blk] = s;
    }
}

__global__ __launch_bounds__(64) void vq_commit(
    const float* __restrict__ ws_commit, float* __restrict__ out)
{
    int b    = blockIdx.x;
    int lane = threadIdx.x;
    float s = (lane < 32) ? ws_commit[b * 32 + lane] : 0.f;
    #pragma unroll
    for (int off = 32; off > 0; off >>= 1) s += __shfl_xor(s, off, 64);
    if (lane == 0)
        out[(size_t)NB * DIN * TT + b] = s * (1.0f / (DCB * TT));
}

extern "C" void kernel_launch(void* const* d_in, const int* in_sizes, int n_in,
                              void* d_out, int out_size, void* d_ws, size_t ws_size,
                              hipStream_t stream) {
    const float* z     = (const float*)d_in[0];
    const float* in_v  = (const float*)d_in[1];
    const float* in_g  = (const float*)d_in[2];
    const float* in_b  = (const float*)d_in[3];
    const float* out_v = (const float*)d_in[4];
    const float* out_g = (const float*)d_in[5];
    const float* out_b = (const float*)d_in[6];
    const float* cb    = (const float*)d_in[7];

    float* ws  = (float*)d_ws;
    float* out = (float*)d_out;

    vq_setup<<<1, 512, 0, stream>>>(in_v, in_g, out_v, out_g, cb, ws);
    vq_main<<<512, 512, 0, stream>>>(z, in_b, out_b, cb, ws, ws + 9216, out);
    vq_commit<<<NB, 64, 0, stream>>>(ws + 9216, out);
}